// Round 5
// baseline (107.647 us; speedup 1.0000x reference)
//
#include <hip/hip_runtime.h>
#include <cfloat>
#include <math.h>

namespace {
constexpr int   B      = 4;
constexpr int   N      = 8192;
constexpr int   KNN    = 16;
constexpr float EPSV   = 1e-12f;

// --- direct-path geometry (main kernel) ---
constexpr int   THREADS = 256;            // 4 waves
constexpr int   WAVES   = THREADS / 64;   // 4
constexpr int   RPW     = 4;              // query rows per wave
constexpr int   RPB     = WAVES * RPW;    // 16 rows per block
constexpr int   BPB     = N / RPB;        // 512 blocks per batch
constexpr int   GRID    = B * BPB;        // 2048
constexpr int   GROUPS  = N / 512;        // 16 candidate groups of 512

// --- fallback (LDS) geometry, proven in R2 ---
constexpr int   THREADS2 = 512;
constexpr int   WAVES2   = THREADS2 / 64; // 8
constexpr int   RPB2     = WAVES2 * RPW;  // 32
constexpr int   BPB2     = N / RPB2;      // 256
constexpr int   GRID2    = B * BPB2;      // 1024
constexpr int   TILE2    = 512;
constexpr int   NTILES2  = N / TILE2;     // 16

constexpr size_t PT4_BYTES = (size_t)B * N * sizeof(float4);   // 512 KB
}

__device__ __forceinline__ float rfl(float x) {
    return __int_as_float(__builtin_amdgcn_readfirstlane(__float_as_int(x)));
}

__device__ __forceinline__ float fast_sqrt(float x) {
#if defined(__has_builtin) && __has_builtin(__builtin_amdgcn_sqrtf)
    return __builtin_amdgcn_sqrtf(x);
#else
    return sqrtf(x);
#endif
}

// ---------- prepass: (x,y,z) -> (x,y,z,|p|^2) ----------
__global__ __launch_bounds__(256)
void knn_prep(const float* __restrict__ pc, float4* __restrict__ pt4)
{
    const int i = blockIdx.x * 256 + threadIdx.x;
    if (i < B * N) {
        const float x = pc[3 * i + 0];
        const float y = pc[3 * i + 1];
        const float z = pc[3 * i + 2];
        pt4[i] = make_float4(x, y, z, fmaf(z, z, fmaf(y, y, x * x)));
    }
}

// ---------- per-lane sorted top-4-of-8 ----------
__device__ __forceinline__ void top4_of_8(const float m[8], float L[4])
{
    const float a0 = fminf(m[0], m[1]), b0 = fmaxf(m[0], m[1]);
    const float a1 = fminf(m[2], m[3]), b1 = fmaxf(m[2], m[3]);
    const float a2 = fminf(m[4], m[5]), b2 = fmaxf(m[4], m[5]);
    const float a3 = fminf(m[6], m[7]), b3 = fmaxf(m[6], m[7]);
    const float p0 = fminf(a0, a1), xP = fmaxf(a0, a1), yP = fminf(b0, b1), p3 = fmaxf(b0, b1);
    const float p1 = fminf(xP, yP), p2 = fmaxf(xP, yP);
    const float q0 = fminf(a2, a3), xQ = fmaxf(a2, a3), yQ = fminf(b2, b3), q3 = fmaxf(b2, b3);
    const float q1 = fminf(xQ, yQ), q2 = fmaxf(xQ, yQ);
    const float l0 = fminf(p0, q3), l1 = fminf(p1, q2), l2 = fminf(p2, q1), l3 = fminf(p3, q0);
    const float t0 = fminf(l0, l2), t2 = fmaxf(l0, l2);
    const float t1 = fminf(l1, l3), t3 = fmaxf(l1, l3);
    L[0] = fminf(t0, t1); L[1] = fmaxf(t0, t1);
    L[2] = fminf(t2, t3); L[3] = fmaxf(t2, t3);
}

// ---------- shared merge tail: pair pre-merge + 16 pops (5-deep chains) ----------
template <int NROWS>
__device__ __forceinline__ float merge_and_sum(float L[NROWS][4], const float* qs)
{
    // lane-pair pre-merge: both lanes of pair (lane^1) keep the exact low-4 of
    // their combined 8 values -> lists duplicated across pairs, chains start at xor 2.
#pragma unroll
    for (int r = 0; r < NROWS; ++r) {
        const float p0 = __shfl_xor(L[r][0], 1, 64);
        const float p1 = __shfl_xor(L[r][1], 1, 64);
        const float p2 = __shfl_xor(L[r][2], 1, 64);
        const float p3 = __shfl_xor(L[r][3], 1, 64);
        const float l0 = fminf(L[r][0], p3), l1 = fminf(L[r][1], p2);
        const float l2 = fminf(L[r][2], p1), l3 = fminf(L[r][3], p0);
        const float t0 = fminf(l0, l2), t2 = fmaxf(l0, l2);
        const float t1 = fminf(l1, l3), t3 = fmaxf(l1, l3);
        L[r][0] = fminf(t0, t1); L[r][1] = fmaxf(t0, t1);
        L[r][2] = fminf(t2, t3); L[r][3] = fmaxf(t2, t3);
    }

    float racc[NROWS];
#pragma unroll
    for (int r = 0; r < NROWS; ++r) racc[r] = 0.0f;

#pragma unroll
    for (int k = 0; k < KNN; ++k) {
#pragma unroll
        for (int r = 0; r < NROWS; ++r) {
            float m = L[r][0];
            m = fminf(m, __shfl_xor(m, 2, 64));
            m = fminf(m, __shfl_xor(m, 4, 64));
            m = fminf(m, __shfl_xor(m, 8, 64));
            m = fminf(m, __shfl_xor(m, 16, 64));
            m = fminf(m, __shfl_xor(m, 32, 64));
            racc[r] += fast_sqrt(fmaxf(qs[r] + m, 0.0f) + EPSV);
            const bool take = (L[r][0] == m);   // duplicated copies pop together
            L[r][0] = take ? L[r][1] : L[r][0];
            L[r][1] = take ? L[r][2] : L[r][1];
            L[r][2] = take ? L[r][3] : L[r][2];
            L[r][3] = take ? FLT_MAX : L[r][3];
        }
    }

    float wsum = 0.0f;
#pragma unroll
    for (int r = 0; r < NROWS; ++r) wsum += racc[r];
    return wsum;
}

// ---------- main kernel: global-direct, reg double-buffer, no barriers ----------
template <int ATOMIC>
__global__ __launch_bounds__(THREADS, 4)     // min 4 waves/EU -> <=128 VGPR
void knn_tv_direct(const float4* __restrict__ pt4, float* __restrict__ outbuf)
{
    __shared__ float sWaveSum[WAVES];

    const int tid   = threadIdx.x;
    const int lane  = tid & 63;
    const int wave  = tid >> 6;
    const int blk   = blockIdx.x;
    const int batch = blk / BPB;
    const int row0  = (blk % BPB) * RPB + wave * RPW;

    const float4* __restrict__ b4 = pt4 + (size_t)batch * (size_t)N;

    float qx[RPW], qy[RPW], qz[RPW], qs[RPW];
#pragma unroll
    for (int r = 0; r < RPW; ++r) {
        const float4 q = b4[row0 + r];
        qx[r] = rfl(-2.0f * q.x);
        qy[r] = rfl(-2.0f * q.y);
        qz[r] = rfl(-2.0f * q.z);
        qs[r] = rfl(q.w);
    }

    float m0[RPW][8];
#pragma unroll
    for (int r = 0; r < RPW; ++r)
#pragma unroll
        for (int j = 0; j < 8; ++j)
            m0[r][j] = FLT_MAX;

    float4 bufA[8], bufB[8];
    // preload group 0
#pragma unroll
    for (int j = 0; j < 8; ++j) bufA[j] = b4[lane + j * 64];

#pragma unroll 1
    for (int g = 0; g < GROUPS; g += 2) {
        const int idx = g * 512 + lane;
        // prefetch group g+1
        if (g + 1 < GROUPS) {
#pragma unroll
            for (int j = 0; j < 8; ++j) bufB[j] = b4[idx + 512 + j * 64];
        }
        // compute group g
#pragma unroll
        for (int r = 0; r < RPW; ++r)
#pragma unroll
            for (int j = 0; j < 8; ++j) {
                const float v = fmaf(bufA[j].x, qx[r],
                                fmaf(bufA[j].y, qy[r],
                                fmaf(bufA[j].z, qz[r], bufA[j].w)));
                m0[r][j] = fminf(m0[r][j], v);
            }
        // prefetch group g+2
        if (g + 2 < GROUPS) {
#pragma unroll
            for (int j = 0; j < 8; ++j) bufA[j] = b4[idx + 1024 + j * 64];
        }
        // compute group g+1
        if (g + 1 < GROUPS) {
#pragma unroll
            for (int r = 0; r < RPW; ++r)
#pragma unroll
                for (int j = 0; j < 8; ++j) {
                    const float v = fmaf(bufB[j].x, qx[r],
                                    fmaf(bufB[j].y, qy[r],
                                    fmaf(bufB[j].z, qz[r], bufB[j].w)));
                    m0[r][j] = fminf(m0[r][j], v);
                }
        }
    }

    float L[RPW][4];
#pragma unroll
    for (int r = 0; r < RPW; ++r) top4_of_8(m0[r], L[r]);

    const float wsum = merge_and_sum<RPW>(L, qs);

    if (lane == 0) sWaveSum[wave] = wsum;
    __syncthreads();
    if (tid == 0) {
        float t = 0.0f;
#pragma unroll
        for (int w = 0; w < WAVES; ++w) t += sWaveSum[w];
        if (ATOMIC) atomicAdd(outbuf, t * (1.0f / (float)(B * N)));
        else        outbuf[blk] = t;
    }
}

// ---------- fallback: LDS-staged kernel (R2 structure) ----------
template <int ATOMIC>
__global__ __launch_bounds__(THREADS2, 1)
void knn_tv_lds(const float* __restrict__ pc, float* __restrict__ outbuf)
{
    __shared__ float sX[TILE2], sY[TILE2], sZ[TILE2], sS[TILE2];
    __shared__ float sWaveSum[WAVES2];

    const int tid   = threadIdx.x;
    const int lane  = tid & 63;
    const int wave  = tid >> 6;
    const int blk   = blockIdx.x;
    const int batch = blk / BPB2;
    const int row0  = (blk % BPB2) * RPB2 + wave * RPW;

    const float* __restrict__ base = pc + (size_t)batch * (size_t)N * 3;

    float qx[RPW], qy[RPW], qz[RPW], qs[RPW];
#pragma unroll
    for (int r = 0; r < RPW; ++r) {
        const int row = row0 + r;
        const float x = base[row * 3 + 0];
        const float y = base[row * 3 + 1];
        const float z = base[row * 3 + 2];
        qx[r] = rfl(-2.0f * x); qy[r] = rfl(-2.0f * y); qz[r] = rfl(-2.0f * z);
        qs[r] = rfl(fmaf(z, z, fmaf(y, y, x * x)));
    }

    float m0[RPW][8];
#pragma unroll
    for (int r = 0; r < RPW; ++r)
#pragma unroll
        for (int c = 0; c < 8; ++c) m0[r][c] = FLT_MAX;

    for (int tile = 0; tile < NTILES2; ++tile) {
        __syncthreads();
        {
            const int p  = tid;
            const int gp = tile * TILE2 + p;
            const float x = base[gp * 3 + 0];
            const float y = base[gp * 3 + 1];
            const float z = base[gp * 3 + 2];
            sX[p] = x; sY[p] = y; sZ[p] = z;
            sS[p] = fmaf(z, z, fmaf(y, y, x * x));
        }
        __syncthreads();

        const int i0 = 4 * lane;
        const int i1 = 256 + 4 * lane;
        const float4 X0 = *(const float4*)&sX[i0], X1 = *(const float4*)&sX[i1];
        const float4 Y0 = *(const float4*)&sY[i0], Y1 = *(const float4*)&sY[i1];
        const float4 Z0 = *(const float4*)&sZ[i0], Z1 = *(const float4*)&sZ[i1];
        const float4 S0 = *(const float4*)&sS[i0], S1 = *(const float4*)&sS[i1];
        const float cx[8] = {X0.x, X0.y, X0.z, X0.w, X1.x, X1.y, X1.z, X1.w};
        const float cy[8] = {Y0.x, Y0.y, Y0.z, Y0.w, Y1.x, Y1.y, Y1.z, Y1.w};
        const float cz[8] = {Z0.x, Z0.y, Z0.z, Z0.w, Z1.x, Z1.y, Z1.z, Z1.w};
        const float cs[8] = {S0.x, S0.y, S0.z, S0.w, S1.x, S1.y, S1.z, S1.w};

#pragma unroll
        for (int r = 0; r < RPW; ++r)
#pragma unroll
            for (int c = 0; c < 8; ++c) {
                const float v = fmaf(cx[c], qx[r], fmaf(cy[c], qy[r], fmaf(cz[c], qz[r], cs[c])));
                m0[r][c] = fminf(m0[r][c], v);
            }
    }

    float L[RPW][4];
#pragma unroll
    for (int r = 0; r < RPW; ++r) top4_of_8(m0[r], L[r]);

    const float wsum = merge_and_sum<RPW>(L, qs);

    if (lane == 0) sWaveSum[wave] = wsum;
    __syncthreads();
    if (tid == 0) {
        float t = 0.0f;
#pragma unroll
        for (int w = 0; w < WAVES2; ++w) t += sWaveSum[w];
        if (ATOMIC) atomicAdd(outbuf, t * (1.0f / (float)(B * N)));
        else        outbuf[blk] = t;
    }
}

__global__ __launch_bounds__(256)
void knn_tv_reduce(const float* __restrict__ partial, float* __restrict__ out, int n)
{
    __shared__ float s[4];
    const int tid = threadIdx.x;
    float v = 0.0f;
    for (int i = tid; i < n; i += 256) v += partial[i];
#pragma unroll
    for (int off = 1; off < 64; off <<= 1) v += __shfl_xor(v, off, 64);
    if ((tid & 63) == 0) s[tid >> 6] = v;
    __syncthreads();
    if (tid == 0) {
        const float t = s[0] + s[1] + s[2] + s[3];
        out[0] = t * (1.0f / (float)(B * N));
    }
}

extern "C" void kernel_launch(void* const* d_in, const int* in_sizes, int n_in,
                              void* d_out, int out_size, void* d_ws, size_t ws_size,
                              hipStream_t stream)
{
    const float* pc  = (const float*)d_in[0];
    float*       out = (float*)d_out;

    if (ws_size >= PT4_BYTES + GRID * sizeof(float)) {
        float4* pt4     = (float4*)d_ws;
        float*  partial = (float*)((char*)d_ws + PT4_BYTES);
        knn_prep<<<(B * N + 255) / 256, 256, 0, stream>>>(pc, pt4);
        knn_tv_direct<0><<<GRID, THREADS, 0, stream>>>(pt4, partial);
        knn_tv_reduce<<<1, 256, 0, stream>>>(partial, out, GRID);
    } else if (ws_size >= GRID2 * sizeof(float)) {
        float* partial = (float*)d_ws;
        knn_tv_lds<0><<<GRID2, THREADS2, 0, stream>>>(pc, partial);
        knn_tv_reduce<<<1, 256, 0, stream>>>(partial, out, GRID2);
    } else {
        hipMemsetAsync(d_out, 0, sizeof(float), stream);
        knn_tv_lds<1><<<GRID2, THREADS2, 0, stream>>>(pc, out);
    }
}

// Round 6
// 84.256 us; speedup vs baseline: 1.2776x; 1.2776x over previous
//
#include <hip/hip_runtime.h>
#include <cfloat>
#include <math.h>

namespace {
constexpr int   B      = 4;
constexpr int   N      = 8192;
constexpr int   KNN    = 16;
constexpr float EPSV   = 1e-12f;

constexpr int   THREADS = 512;            // 8 waves
constexpr int   WAVES   = THREADS / 64;   // 8
constexpr int   RPW     = 8;              // query rows per wave (was 4)
constexpr int   RPB     = WAVES * RPW;    // 64 rows per block
constexpr int   BPB     = N / RPB;        // 128 blocks per batch
constexpr int   GRID    = B * BPB;        // 512
constexpr int   TILE    = 1024;           // candidates per LDS tile
constexpr int   NTILES  = N / TILE;       // 8
}

__device__ __forceinline__ float rfl(float x) {
    return __int_as_float(__builtin_amdgcn_readfirstlane(__float_as_int(x)));
}

__device__ __forceinline__ float fast_sqrt(float x) {
#if defined(__has_builtin) && __has_builtin(__builtin_amdgcn_sqrtf)
    return __builtin_amdgcn_sqrtf(x);
#else
    return sqrtf(x);
#endif
}

// ---------- per-lane sorted top-4-of-8 ----------
__device__ __forceinline__ void top4_of_8(const float m[8], float L[4])
{
    const float a0 = fminf(m[0], m[1]), b0 = fmaxf(m[0], m[1]);
    const float a1 = fminf(m[2], m[3]), b1 = fmaxf(m[2], m[3]);
    const float a2 = fminf(m[4], m[5]), b2 = fmaxf(m[4], m[5]);
    const float a3 = fminf(m[6], m[7]), b3 = fmaxf(m[6], m[7]);
    const float p0 = fminf(a0, a1), xP = fmaxf(a0, a1), yP = fminf(b0, b1), p3 = fmaxf(b0, b1);
    const float p1 = fminf(xP, yP), p2 = fmaxf(xP, yP);
    const float q0 = fminf(a2, a3), xQ = fmaxf(a2, a3), yQ = fminf(b2, b3), q3 = fmaxf(b2, b3);
    const float q1 = fminf(xQ, yQ), q2 = fmaxf(xQ, yQ);
    const float l0 = fminf(p0, q3), l1 = fminf(p1, q2), l2 = fminf(p2, q1), l3 = fminf(p3, q0);
    const float t0 = fminf(l0, l2), t2 = fmaxf(l0, l2);
    const float t1 = fminf(l1, l3), t3 = fmaxf(l1, l3);
    L[0] = fminf(t0, t1); L[1] = fmaxf(t0, t1);
    L[2] = fminf(t2, t3); L[3] = fmaxf(t2, t3);
}

// ---------- merge tail: lane-pair pre-merge + 16 pops (5-deep chains) ----------
template <int NROWS>
__device__ __forceinline__ float merge_and_sum(float L[NROWS][4], const float* qs)
{
    // lane-pair pre-merge: lanes l and l^1 both keep the exact low-4 of their
    // combined 8 values (lists duplicated) -> pop chains start at xor 2.
#pragma unroll
    for (int r = 0; r < NROWS; ++r) {
        const float p0 = __shfl_xor(L[r][0], 1, 64);
        const float p1 = __shfl_xor(L[r][1], 1, 64);
        const float p2 = __shfl_xor(L[r][2], 1, 64);
        const float p3 = __shfl_xor(L[r][3], 1, 64);
        const float l0 = fminf(L[r][0], p3), l1 = fminf(L[r][1], p2);
        const float l2 = fminf(L[r][2], p1), l3 = fminf(L[r][3], p0);
        const float t0 = fminf(l0, l2), t2 = fmaxf(l0, l2);
        const float t1 = fminf(l1, l3), t3 = fmaxf(l1, l3);
        L[r][0] = fminf(t0, t1); L[r][1] = fmaxf(t0, t1);
        L[r][2] = fminf(t2, t3); L[r][3] = fmaxf(t2, t3);
    }

    float racc[NROWS];
#pragma unroll
    for (int r = 0; r < NROWS; ++r) racc[r] = 0.0f;

#pragma unroll
    for (int k = 0; k < KNN; ++k) {
#pragma unroll
        for (int r = 0; r < NROWS; ++r) {    // r-inner: NROWS chains interleave
            float m = L[r][0];
            m = fminf(m, __shfl_xor(m, 2, 64));
            m = fminf(m, __shfl_xor(m, 4, 64));
            m = fminf(m, __shfl_xor(m, 8, 64));
            m = fminf(m, __shfl_xor(m, 16, 64));
            m = fminf(m, __shfl_xor(m, 32, 64));
            racc[r] += fast_sqrt(fmaxf(qs[r] + m, 0.0f) + EPSV);
            const bool take = (L[r][0] == m);   // duplicated copies pop together
            L[r][0] = take ? L[r][1] : L[r][0];
            L[r][1] = take ? L[r][2] : L[r][1];
            L[r][2] = take ? L[r][3] : L[r][2];
            L[r][3] = take ? FLT_MAX : L[r][3];
        }
    }

    float wsum = 0.0f;
#pragma unroll
    for (int r = 0; r < NROWS; ++r) wsum += racc[r];
    return wsum;
}

// ---------- main kernel: LDS-staged, 8 rows/wave, 8 stream-slots/lane ----------
template <int ATOMIC>
__global__ __launch_bounds__(THREADS)
__attribute__((amdgpu_waves_per_eu(2, 4)))   // cap 256 VGPR, aim 4 waves/EU: no spills
void knn_tv_kernel(const float* __restrict__ pc, float* __restrict__ outbuf)
{
    __shared__ float sX[TILE], sY[TILE], sZ[TILE], sS[TILE];   // 16 KB SoA
    __shared__ float sWaveSum[WAVES];

    const int tid   = threadIdx.x;
    const int lane  = tid & 63;
    const int wave  = tid >> 6;
    const int blk   = blockIdx.x;
    const int batch = blk / BPB;
    const int row0  = (blk % BPB) * RPB + wave * RPW;

    const float* __restrict__ base = pc + (size_t)batch * (size_t)N * 3;

    // query scalars -> SGPR (wave-uniform); fold -2 into q, re-add |q|^2 at pop
    float qx[RPW], qy[RPW], qz[RPW], qs[RPW];
#pragma unroll
    for (int r = 0; r < RPW; ++r) {
        const int row = row0 + r;
        const float x = base[row * 3 + 0];
        const float y = base[row * 3 + 1];
        const float z = base[row * 3 + 2];
        qx[r] = rfl(-2.0f * x);
        qy[r] = rfl(-2.0f * y);
        qz[r] = rfl(-2.0f * z);
        qs[r] = rfl(fmaf(z, z, fmaf(y, y, x * x)));
    }

    // per-(lane, slot) stream minima of v = |c|^2 - 2 q.c  (8 slots/lane = 512 streams)
    float m0[RPW][8];
#pragma unroll
    for (int r = 0; r < RPW; ++r)
#pragma unroll
        for (int j = 0; j < 8; ++j)
            m0[r][j] = FLT_MAX;

    for (int tile = 0; tile < NTILES; ++tile) {
        __syncthreads();   // protect SoA from previous tile's readers
        // stage 1024 candidates: 2 points per thread
#pragma unroll
        for (int h = 0; h < 2; ++h) {
            const int p  = tid + h * THREADS;
            const int gp = tile * TILE + p;
            const float x = base[gp * 3 + 0];
            const float y = base[gp * 3 + 1];
            const float z = base[gp * 3 + 2];
            sX[p] = x; sY[p] = y; sZ[p] = z;
            sS[p] = fmaf(z, z, fmaf(y, y, x * x));
        }
        __syncthreads();

        // 4 groups of 256; group parity selects slot nibble (16 groups/parity overall)
#pragma unroll
        for (int grp = 0; grp < 4; ++grp) {
            const int o = grp * 256 + 4 * lane;
            const float4 CX = *(const float4*)&sX[o];
            const float4 CY = *(const float4*)&sY[o];
            const float4 CZ = *(const float4*)&sZ[o];
            const float4 CS = *(const float4*)&sS[o];
            const float cx[4] = {CX.x, CX.y, CX.z, CX.w};
            const float cy[4] = {CY.x, CY.y, CY.z, CY.w};
            const float cz[4] = {CZ.x, CZ.y, CZ.z, CZ.w};
            const float cs[4] = {CS.x, CS.y, CS.z, CS.w};
            const int jb = (grp & 1) * 4;
#pragma unroll
            for (int r = 0; r < RPW; ++r)
#pragma unroll
                for (int i = 0; i < 4; ++i) {
                    const float v = fmaf(cx[i], qx[r],
                                    fmaf(cy[i], qy[r],
                                    fmaf(cz[i], qz[r], cs[i])));
                    m0[r][jb + i] = fminf(m0[r][jb + i], v);
                }
        }
    }

    float L[RPW][4];
#pragma unroll
    for (int r = 0; r < RPW; ++r) top4_of_8(m0[r], L[r]);

    const float wsum = merge_and_sum<RPW>(L, qs);

    if (lane == 0) sWaveSum[wave] = wsum;
    __syncthreads();
    if (tid == 0) {
        float t = 0.0f;
#pragma unroll
        for (int w = 0; w < WAVES; ++w) t += sWaveSum[w];
        if (ATOMIC) atomicAdd(outbuf, t * (1.0f / (float)(B * N)));
        else        outbuf[blk] = t;
    }
}

__global__ __launch_bounds__(256)
void knn_tv_reduce(const float* __restrict__ partial, float* __restrict__ out, int n)
{
    __shared__ float s[4];
    const int tid = threadIdx.x;
    float v = 0.0f;
    for (int i = tid; i < n; i += 256) v += partial[i];
#pragma unroll
    for (int off = 1; off < 64; off <<= 1) v += __shfl_xor(v, off, 64);
    if ((tid & 63) == 0) s[tid >> 6] = v;
    __syncthreads();
    if (tid == 0) {
        const float t = s[0] + s[1] + s[2] + s[3];
        out[0] = t * (1.0f / (float)(B * N));
    }
}

extern "C" void kernel_launch(void* const* d_in, const int* in_sizes, int n_in,
                              void* d_out, int out_size, void* d_ws, size_t ws_size,
                              hipStream_t stream)
{
    const float* pc  = (const float*)d_in[0];
    float*       out = (float*)d_out;

    if (ws_size >= GRID * sizeof(float)) {
        float* partial = (float*)d_ws;
        knn_tv_kernel<0><<<GRID, THREADS, 0, stream>>>(pc, partial);
        knn_tv_reduce<<<1, 256, 0, stream>>>(partial, out, GRID);
    } else {
        hipMemsetAsync(d_out, 0, sizeof(float), stream);
        knn_tv_kernel<1><<<GRID, THREADS, 0, stream>>>(pc, out);
    }
}

// Round 7
// 82.445 us; speedup vs baseline: 1.3057x; 1.0220x over previous
//
#include <hip/hip_runtime.h>
#include <cfloat>
#include <math.h>

namespace {
constexpr int   B      = 4;
constexpr int   N      = 8192;
constexpr int   KNN    = 16;
constexpr float EPSV   = 1e-12f;

// --- 1-wave-block direct kernel geometry ---
constexpr int   RPW    = 8;               // query rows per wave
constexpr int   WPB    = N / RPW;         // 1024 waves per batch
constexpr int   GRID   = B * WPB;         // 4096 blocks (1 wave each)
constexpr int   GROUPS = N / 256;         // 32 groups of 256 candidates

// --- fallback (LDS) geometry (R5 kernel, proven) ---
constexpr int   THREADS2 = 512;
constexpr int   WAVES2   = THREADS2 / 64;
constexpr int   RPB2     = WAVES2 * RPW;  // 64
constexpr int   BPB2     = N / RPB2;      // 128
constexpr int   GRID2    = B * BPB2;      // 512
constexpr int   TILE2    = 1024;
constexpr int   NTILES2  = N / TILE2;

constexpr size_t PT4_BYTES = (size_t)B * N * sizeof(float4);   // 512 KB
}

__device__ __forceinline__ float rfl(float x) {
    return __int_as_float(__builtin_amdgcn_readfirstlane(__float_as_int(x)));
}

__device__ __forceinline__ float fast_sqrt(float x) {
#if defined(__has_builtin) && __has_builtin(__builtin_amdgcn_sqrtf)
    return __builtin_amdgcn_sqrtf(x);
#else
    return sqrtf(x);
#endif
}

// ---------- prepass: (x,y,z) -> (x,y,z,|p|^2) ----------
__global__ __launch_bounds__(256)
void knn_prep(const float* __restrict__ pc, float4* __restrict__ pt4)
{
    const int i = blockIdx.x * 256 + threadIdx.x;
    if (i < B * N) {
        const float x = pc[3 * i + 0];
        const float y = pc[3 * i + 1];
        const float z = pc[3 * i + 2];
        pt4[i] = make_float4(x, y, z, fmaf(z, z, fmaf(y, y, x * x)));
    }
}

// ---------- per-lane sorted top-4-of-8 ----------
__device__ __forceinline__ void top4_of_8(const float m[8], float L[4])
{
    const float a0 = fminf(m[0], m[1]), b0 = fmaxf(m[0], m[1]);
    const float a1 = fminf(m[2], m[3]), b1 = fmaxf(m[2], m[3]);
    const float a2 = fminf(m[4], m[5]), b2 = fmaxf(m[4], m[5]);
    const float a3 = fminf(m[6], m[7]), b3 = fmaxf(m[6], m[7]);
    const float p0 = fminf(a0, a1), xP = fmaxf(a0, a1), yP = fminf(b0, b1), p3 = fmaxf(b0, b1);
    const float p1 = fminf(xP, yP), p2 = fmaxf(xP, yP);
    const float q0 = fminf(a2, a3), xQ = fmaxf(a2, a3), yQ = fminf(b2, b3), q3 = fmaxf(b2, b3);
    const float q1 = fminf(xQ, yQ), q2 = fmaxf(xQ, yQ);
    const float l0 = fminf(p0, q3), l1 = fminf(p1, q2), l2 = fminf(p2, q1), l3 = fminf(p3, q0);
    const float t0 = fminf(l0, l2), t2 = fmaxf(l0, l2);
    const float t1 = fminf(l1, l3), t3 = fmaxf(l1, l3);
    L[0] = fminf(t0, t1); L[1] = fmaxf(t0, t1);
    L[2] = fminf(t2, t3); L[3] = fmaxf(t2, t3);
}

// ---------- merge tail: lane-pair pre-merge + 16 pops (5-deep chains) ----------
template <int NROWS>
__device__ __forceinline__ float merge_and_sum(float L[NROWS][4], const float* qs)
{
#pragma unroll
    for (int r = 0; r < NROWS; ++r) {
        const float p0 = __shfl_xor(L[r][0], 1, 64);
        const float p1 = __shfl_xor(L[r][1], 1, 64);
        const float p2 = __shfl_xor(L[r][2], 1, 64);
        const float p3 = __shfl_xor(L[r][3], 1, 64);
        const float l0 = fminf(L[r][0], p3), l1 = fminf(L[r][1], p2);
        const float l2 = fminf(L[r][2], p1), l3 = fminf(L[r][3], p0);
        const float t0 = fminf(l0, l2), t2 = fmaxf(l0, l2);
        const float t1 = fminf(l1, l3), t3 = fmaxf(l1, l3);
        L[r][0] = fminf(t0, t1); L[r][1] = fmaxf(t0, t1);
        L[r][2] = fminf(t2, t3); L[r][3] = fmaxf(t2, t3);
    }

    float racc[NROWS];
#pragma unroll
    for (int r = 0; r < NROWS; ++r) racc[r] = 0.0f;

#pragma unroll
    for (int k = 0; k < KNN; ++k) {
#pragma unroll
        for (int r = 0; r < NROWS; ++r) {
            float m = L[r][0];
            m = fminf(m, __shfl_xor(m, 2, 64));
            m = fminf(m, __shfl_xor(m, 4, 64));
            m = fminf(m, __shfl_xor(m, 8, 64));
            m = fminf(m, __shfl_xor(m, 16, 64));
            m = fminf(m, __shfl_xor(m, 32, 64));
            racc[r] += fast_sqrt(fmaxf(qs[r] + m, 0.0f) + EPSV);
            const bool take = (L[r][0] == m);
            L[r][0] = take ? L[r][1] : L[r][0];
            L[r][1] = take ? L[r][2] : L[r][1];
            L[r][2] = take ? L[r][3] : L[r][2];
            L[r][3] = take ? FLT_MAX : L[r][3];
        }
    }

    float wsum = 0.0f;
#pragma unroll
    for (int r = 0; r < NROWS; ++r) wsum += racc[r];
    return wsum;
}

// ---------- main kernel: one wave per block, no LDS, no barriers ----------
template <int ATOMIC>
__global__ __launch_bounds__(64)
__attribute__((amdgpu_waves_per_eu(4, 8)))   // cap 128 VGPR; 4 waves/SIMD -> full grid resident
void knn_tv_wave(const float4* __restrict__ pt4, float* __restrict__ outbuf)
{
    const int lane  = threadIdx.x;        // 0..63 (one wave)
    const int blk   = blockIdx.x;
    const int batch = blk / WPB;
    const int row0  = (blk % WPB) * RPW;

    const float4* __restrict__ b4 = pt4 + (size_t)batch * (size_t)N;

    // query scalars -> SGPR (wave-uniform); fold -2 into q, re-add |q|^2 at pop
    float qx[RPW], qy[RPW], qz[RPW], qs[RPW];
#pragma unroll
    for (int r = 0; r < RPW; ++r) {
        const float4 q = b4[row0 + r];
        qx[r] = rfl(-2.0f * q.x);
        qy[r] = rfl(-2.0f * q.y);
        qz[r] = rfl(-2.0f * q.z);
        qs[r] = rfl(q.w);
    }

    // per-(lane, slot) stream minima of v = |c|^2 - 2 q.c  (8 slots/lane = 512 streams)
    float m0[RPW][8];
#pragma unroll
    for (int r = 0; r < RPW; ++r)
#pragma unroll
        for (int j = 0; j < 8; ++j)
            m0[r][j] = FLT_MAX;

    // 32 groups of 256 candidates; 4 float4 loads (16 VGPR) in flight per group,
    // each load feeds RPW*4 = 32 VALU ops. Group parity selects the slot nibble.
    const float4* __restrict__ p = b4 + lane;
#pragma unroll 2
    for (int g = 0; g < GROUPS; ++g) {
        const float4 a0 = p[g * 256 +   0];
        const float4 a1 = p[g * 256 +  64];
        const float4 a2 = p[g * 256 + 128];
        const float4 a3 = p[g * 256 + 192];
        const float cx[4] = {a0.x, a1.x, a2.x, a3.x};
        const float cy[4] = {a0.y, a1.y, a2.y, a3.y};
        const float cz[4] = {a0.z, a1.z, a2.z, a3.z};
        const float cs[4] = {a0.w, a1.w, a2.w, a3.w};
        const int jb = (g & 1) * 4;
#pragma unroll
        for (int r = 0; r < RPW; ++r)
#pragma unroll
            for (int i = 0; i < 4; ++i) {
                const float v = fmaf(cx[i], qx[r],
                                fmaf(cy[i], qy[r],
                                fmaf(cz[i], qz[r], cs[i])));
                m0[r][jb + i] = fminf(m0[r][jb + i], v);
            }
    }

    float L[RPW][4];
#pragma unroll
    for (int r = 0; r < RPW; ++r) top4_of_8(m0[r], L[r]);

    const float wsum = merge_and_sum<RPW>(L, qs);

    if (lane == 0) {
        if (ATOMIC) atomicAdd(outbuf, wsum * (1.0f / (float)(B * N)));
        else        outbuf[blk] = wsum;
    }
}

// ---------- fallback: R5's LDS-staged kernel ----------
template <int ATOMIC>
__global__ __launch_bounds__(THREADS2)
__attribute__((amdgpu_waves_per_eu(2, 4)))
void knn_tv_lds(const float* __restrict__ pc, float* __restrict__ outbuf)
{
    __shared__ float sX[TILE2], sY[TILE2], sZ[TILE2], sS[TILE2];
    __shared__ float sWaveSum[WAVES2];

    const int tid   = threadIdx.x;
    const int lane  = tid & 63;
    const int wave  = tid >> 6;
    const int blk   = blockIdx.x;
    const int batch = blk / BPB2;
    const int row0  = (blk % BPB2) * RPB2 + wave * RPW;

    const float* __restrict__ base = pc + (size_t)batch * (size_t)N * 3;

    float qx[RPW], qy[RPW], qz[RPW], qs[RPW];
#pragma unroll
    for (int r = 0; r < RPW; ++r) {
        const int row = row0 + r;
        const float x = base[row * 3 + 0];
        const float y = base[row * 3 + 1];
        const float z = base[row * 3 + 2];
        qx[r] = rfl(-2.0f * x); qy[r] = rfl(-2.0f * y); qz[r] = rfl(-2.0f * z);
        qs[r] = rfl(fmaf(z, z, fmaf(y, y, x * x)));
    }

    float m0[RPW][8];
#pragma unroll
    for (int r = 0; r < RPW; ++r)
#pragma unroll
        for (int c = 0; c < 8; ++c) m0[r][c] = FLT_MAX;

    for (int tile = 0; tile < NTILES2; ++tile) {
        __syncthreads();
#pragma unroll
        for (int h = 0; h < 2; ++h) {
            const int p  = tid + h * THREADS2;
            const int gp = tile * TILE2 + p;
            const float x = base[gp * 3 + 0];
            const float y = base[gp * 3 + 1];
            const float z = base[gp * 3 + 2];
            sX[p] = x; sY[p] = y; sZ[p] = z;
            sS[p] = fmaf(z, z, fmaf(y, y, x * x));
        }
        __syncthreads();

#pragma unroll
        for (int grp = 0; grp < 4; ++grp) {
            const int o = grp * 256 + 4 * lane;
            const float4 CX = *(const float4*)&sX[o];
            const float4 CY = *(const float4*)&sY[o];
            const float4 CZ = *(const float4*)&sZ[o];
            const float4 CS = *(const float4*)&sS[o];
            const float cx[4] = {CX.x, CX.y, CX.z, CX.w};
            const float cy[4] = {CY.x, CY.y, CY.z, CY.w};
            const float cz[4] = {CZ.x, CZ.y, CZ.z, CZ.w};
            const float cs[4] = {CS.x, CS.y, CS.z, CS.w};
            const int jb = (grp & 1) * 4;
#pragma unroll
            for (int r = 0; r < RPW; ++r)
#pragma unroll
                for (int i = 0; i < 4; ++i) {
                    const float v = fmaf(cx[i], qx[r], fmaf(cy[i], qy[r], fmaf(cz[i], qz[r], cs[i])));
                    m0[r][jb + i] = fminf(m0[r][jb + i], v);
                }
        }
    }

    float L[RPW][4];
#pragma unroll
    for (int r = 0; r < RPW; ++r) top4_of_8(m0[r], L[r]);

    const float wsum = merge_and_sum<RPW>(L, qs);

    if (lane == 0) sWaveSum[wave] = wsum;
    __syncthreads();
    if (tid == 0) {
        float t = 0.0f;
#pragma unroll
        for (int w = 0; w < WAVES2; ++w) t += sWaveSum[w];
        if (ATOMIC) atomicAdd(outbuf, t * (1.0f / (float)(B * N)));
        else        outbuf[blk] = t;
    }
}

__global__ __launch_bounds__(256)
void knn_tv_reduce(const float* __restrict__ partial, float* __restrict__ out, int n)
{
    __shared__ float s[4];
    const int tid = threadIdx.x;
    float v = 0.0f;
    for (int i = tid; i < n; i += 256) v += partial[i];
#pragma unroll
    for (int off = 1; off < 64; off <<= 1) v += __shfl_xor(v, off, 64);
    if ((tid & 63) == 0) s[tid >> 6] = v;
    __syncthreads();
    if (tid == 0) {
        const float t = s[0] + s[1] + s[2] + s[3];
        out[0] = t * (1.0f / (float)(B * N));
    }
}

extern "C" void kernel_launch(void* const* d_in, const int* in_sizes, int n_in,
                              void* d_out, int out_size, void* d_ws, size_t ws_size,
                              hipStream_t stream)
{
    const float* pc  = (const float*)d_in[0];
    float*       out = (float*)d_out;

    if (ws_size >= PT4_BYTES + GRID * sizeof(float)) {
        float4* pt4     = (float4*)d_ws;
        float*  partial = (float*)((char*)d_ws + PT4_BYTES);
        knn_prep<<<(B * N + 255) / 256, 256, 0, stream>>>(pc, pt4);
        knn_tv_wave<0><<<GRID, 64, 0, stream>>>(pt4, partial);
        knn_tv_reduce<<<1, 256, 0, stream>>>(partial, out, GRID);
    } else if (ws_size >= GRID2 * sizeof(float)) {
        float* partial = (float*)d_ws;
        knn_tv_lds<0><<<GRID2, THREADS2, 0, stream>>>(pc, partial);
        knn_tv_reduce<<<1, 256, 0, stream>>>(partial, out, GRID2);
    } else {
        hipMemsetAsync(d_out, 0, sizeof(float), stream);
        knn_tv_lds<1><<<GRID2, THREADS2, 0, stream>>>(pc, out);
    }
}